// Round 1
// baseline (46.947 us; speedup 1.0000x reference)
//
#include <hip/hip_runtime.h>

// Problem constants (match reference setup_inputs)
constexpr int T_DIM = 512;
constexpr int B_DIM = 32;
constexpr int L_DIM = 64;
constexpr int V_DIM = 10000;

// Zero the scalar output each launch (harness poisons once, never re-poisons).
__global__ void ACE_zero_k(float* out) {
    if (threadIdx.x == 0 && blockIdx.x == 0) out[0] = 0.0f;
}

// One wave per (batch, entry) pair.
// entry 0           -> blank symbol v=0, weight = T - (#nonzero labels in batch)
// entry i in 1..64  -> v = label[b][i-1], weight 1 (skipped if label == 0)
__global__ __launch_bounds__(64) void ACE_sparse_loss_k(const float* __restrict__ x,
                                                        const int* __restrict__ label,
                                                        float* __restrict__ out) {
    const int e    = blockIdx.x;
    const int b    = e / (L_DIM + 1);
    const int i    = e % (L_DIM + 1);
    const int lane = threadIdx.x;  // 0..63

    int v, wcount;
    if (i == 0) {
        // All 64 lanes read one label each (L == wave size), ballot-count nonzeros.
        int lab = label[b * L_DIM + lane];
        unsigned long long nz = __ballot(lab != 0);
        int len = __popcll(nz);
        v = 0;
        wcount = T_DIM - len;
    } else {
        int li = label[b * L_DIM + (i - 1)];  // uniform broadcast load
        if (li == 0) return;                  // masked label; wave-uniform exit
        v = li;
        wcount = 1;
    }

    // Column sum over T: lane handles t = lane, lane+64, ..., lane+448.
    const float* p = x + (size_t)b * V_DIM + v;
    float s = 0.0f;
#pragma unroll
    for (int k = 0; k < T_DIM / 64; ++k) {
        s += p[(size_t)(lane + 64 * k) * ((size_t)B_DIM * V_DIM)];
    }

    // Wave-64 shuffle reduction.
#pragma unroll
    for (int off = 32; off; off >>= 1) s += __shfl_down(s, off);

    if (lane == 0) {
        float xavg = s * (1.0f / T_DIM) + 1e-10f;
        float contrib = -(float)wcount * logf(xavg) * (1.0f / ((float)T_DIM * (float)B_DIM));
        atomicAdd(out, contrib);
    }
}

extern "C" void kernel_launch(void* const* d_in, const int* in_sizes, int n_in,
                              void* d_out, int out_size, void* d_ws, size_t ws_size,
                              hipStream_t stream) {
    const float* x     = (const float*)d_in[0];  // [T, B, V] float32
    const int*   label = (const int*)d_in[1];    // [B, L] int
    float* out = (float*)d_out;                  // scalar loss

    ACE_zero_k<<<1, 64, 0, stream>>>(out);

    const int n_entries = B_DIM * (L_DIM + 1);   // 2080
    ACE_sparse_loss_k<<<n_entries, 64, 0, stream>>>(x, label, out);
}

// Round 2
// 35.688 us; speedup vs baseline: 1.3155x; 1.3155x over previous
//
#include <hip/hip_runtime.h>

// Problem constants (match reference setup_inputs)
constexpr int T_DIM = 512;
constexpr int B_DIM = 32;
constexpr int L_DIM = 64;   // == wave size
constexpr int V_DIM = 10000;
constexpr int TC    = 32;            // t-chunks per batch
constexpr int T_PER_BLOCK = T_DIM / TC;  // 16 t's per block
constexpr int T_PER_WAVE  = T_PER_BLOCK / 4; // 4 t's per wave (256-thread block)

// Kernel 1: per-(b, t-chunk) partial column sums for the 64 label entries
// plus the blank (v=0) column. Row-major gather: each wave's 64 lanes read
// within ONE contiguous 40KB row x[t,b,:], giving DRAM page/channel locality.
// Writes: part_label[(b*TC + tc)*64 + lane], part_blank[b*TC + tc].
// No atomics; every slot written unconditionally each launch.
__global__ __launch_bounds__(256) void ACE_gather_k(const float* __restrict__ x,
                                                    const int* __restrict__ label,
                                                    float* __restrict__ part_label,
                                                    float* __restrict__ part_blank) {
    const int b    = blockIdx.x;   // 0..31
    const int tc   = blockIdx.y;   // 0..31
    const int tid  = threadIdx.x;  // 0..255
    const int w    = tid >> 6;     // wave 0..3
    const int lane = tid & 63;

    __shared__ float lds[256];
    __shared__ float ldsb[T_PER_BLOCK];

    // Blank column partial: threads 0..15 each load one x[t,b,0].
    if (tid < T_PER_BLOCK) {
        size_t t = (size_t)tc * T_PER_BLOCK + tid;
        ldsb[tid] = x[(t * B_DIM + b) * V_DIM];
    }

    const int lab = label[b * L_DIM + lane];

    float s = 0.0f;
    if (lab != 0) {
        const int t0 = tc * T_PER_BLOCK + w * T_PER_WAVE;
        const float* p = x + ((size_t)t0 * B_DIM + b) * V_DIM + lab;
#pragma unroll
        for (int k = 0; k < T_PER_WAVE; ++k) {
            s += p[(size_t)k * B_DIM * V_DIM];
        }
    }
    lds[tid] = s;
    __syncthreads();

    if (tid < 64) {
        float tot = lds[tid] + lds[tid + 64] + lds[tid + 128] + lds[tid + 192];
        part_label[((size_t)b * TC + tc) * 64 + tid] = tot;
    }
    if (tid == 0) {
        float bs = 0.0f;
#pragma unroll
        for (int k = 0; k < T_PER_BLOCK; ++k) bs += ldsb[k];
        part_blank[b * TC + tc] = bs;
    }
}

// Kernel 2: single-block finalize. Sums the TC partials per (b, entry),
// applies -w*log(avg + 1e-10), reduces to the scalar loss. Deterministic.
__global__ __launch_bounds__(256) void ACE_finalize_k(const float* __restrict__ part_label,
                                                      const float* __restrict__ part_blank,
                                                      const int* __restrict__ label,
                                                      float* __restrict__ out) {
    const int tid  = threadIdx.x;
    const int w    = tid >> 6;
    const int lane = tid & 63;

    float local = 0.0f;
    for (int j = 0; j < B_DIM / 4; ++j) {
        const int b = w * (B_DIM / 4) + j;
        const int lab = label[b * L_DIM + lane];

        if (lab != 0) {
            float tot = 0.0f;
#pragma unroll
            for (int tc = 0; tc < TC; ++tc)
                tot += part_label[((size_t)b * TC + tc) * 64 + lane];
            local += -logf(tot * (1.0f / T_DIM) + 1e-10f);
        }

        unsigned long long nz = __ballot(lab != 0);
        if (lane == 0) {
            int len = __popcll(nz);
            float bs = 0.0f;
#pragma unroll
            for (int tc = 0; tc < TC; ++tc) bs += part_blank[b * TC + tc];
            local += -(float)(T_DIM - len) * logf(bs * (1.0f / T_DIM) + 1e-10f);
        }
    }

    // Wave-64 reduction, then cross-wave via LDS.
#pragma unroll
    for (int off = 32; off; off >>= 1) local += __shfl_down(local, off);

    __shared__ float r[4];
    if (lane == 0) r[w] = local;
    __syncthreads();
    if (tid == 0)
        out[0] = (r[0] + r[1] + r[2] + r[3]) * (1.0f / ((float)T_DIM * (float)B_DIM));
}

extern "C" void kernel_launch(void* const* d_in, const int* in_sizes, int n_in,
                              void* d_out, int out_size, void* d_ws, size_t ws_size,
                              hipStream_t stream) {
    const float* x     = (const float*)d_in[0];  // [T, B, V] float32
    const int*   label = (const int*)d_in[1];    // [B, L] int
    float* out = (float*)d_out;

    float* part_label = (float*)d_ws;                          // 32*32*64 floats = 256 KB
    float* part_blank = part_label + (size_t)B_DIM * TC * 64;  // 1024 floats

    dim3 grid(B_DIM, TC);
    ACE_gather_k<<<grid, 256, 0, stream>>>(x, label, part_label, part_blank);
    ACE_finalize_k<<<1, 256, 0, stream>>>(part_label, part_blank, label, out);
}

// Round 3
// 29.631 us; speedup vs baseline: 1.5844x; 1.2044x over previous
//
#include <hip/hip_runtime.h>

// Problem constants (match reference setup_inputs)
constexpr int T_DIM = 512;
constexpr int B_DIM = 32;
constexpr int L_DIM = 64;   // == wave size
constexpr int V_DIM = 10000;
constexpr int TC    = 32;            // t-chunks per batch
constexpr int T_PER_BLOCK = T_DIM / TC;      // 16 t's per block
constexpr int T_PER_WAVE  = T_PER_BLOCK / 4; // 4 t's per wave (256-thread block)

// Kernel 1 (unchanged from R2): per-(b, t-chunk) partial column sums for the
// 64 label entries plus the blank (v=0) column. Row-major gather: each wave's
// 64 lanes read within ONE contiguous 40KB row x[t,b,:]. DRAM-line-bound:
// ~1.06M distinct 128B lines ~= 135 MB -> ~21.5us floor at 6.3 TB/s.
__global__ __launch_bounds__(256) void ACE_gather_k(const float* __restrict__ x,
                                                    const int* __restrict__ label,
                                                    float* __restrict__ part_label,
                                                    float* __restrict__ part_blank) {
    const int b    = blockIdx.x;   // 0..31
    const int tc   = blockIdx.y;   // 0..31
    const int tid  = threadIdx.x;  // 0..255
    const int w    = tid >> 6;     // wave 0..3
    const int lane = tid & 63;

    __shared__ float lds[256];
    __shared__ float ldsb[T_PER_BLOCK];

    // Blank column partial: threads 0..15 each load one x[t,b,0].
    if (tid < T_PER_BLOCK) {
        size_t t = (size_t)tc * T_PER_BLOCK + tid;
        ldsb[tid] = x[(t * B_DIM + b) * V_DIM];
    }

    const int lab = label[b * L_DIM + lane];

    float s = 0.0f;
    if (lab != 0) {
        const int t0 = tc * T_PER_BLOCK + w * T_PER_WAVE;
        const float* p = x + ((size_t)t0 * B_DIM + b) * V_DIM + lab;
#pragma unroll
        for (int k = 0; k < T_PER_WAVE; ++k) {
            s += p[(size_t)k * B_DIM * V_DIM];
        }
    }
    lds[tid] = s;
    __syncthreads();

    if (tid < 64) {
        float tot = lds[tid] + lds[tid + 64] + lds[tid + 128] + lds[tid + 192];
        part_label[((size_t)b * TC + tc) * 64 + tid] = tot;
    }
    if (tid == 0) {
        float bs = 0.0f;
#pragma unroll
        for (int k = 0; k < T_PER_BLOCK; ++k) bs += ldsb[k];
        part_blank[b * TC + tc] = bs;
    }
}

// Kernel 2: widened finalize — 1024 threads / 16 waves, each wave owns 2
// batches. Coalesced 256B loads, TC-deep unroll for latency hiding.
// Deterministic scalar write; no atomics.
__global__ __launch_bounds__(1024) void ACE_finalize_k(const float* __restrict__ part_label,
                                                       const float* __restrict__ part_blank,
                                                       const int* __restrict__ label,
                                                       float* __restrict__ out) {
    const int tid  = threadIdx.x;
    const int w    = tid >> 6;     // 0..15
    const int lane = tid & 63;

    float local = 0.0f;
#pragma unroll
    for (int j = 0; j < 2; ++j) {
        const int b = w * 2 + j;
        const int lab = label[b * L_DIM + lane];

        // Unconditional coalesced partial-sum load (keeps loads uniform).
        float tot = 0.0f;
#pragma unroll
        for (int tc = 0; tc < TC; ++tc)
            tot += part_label[((size_t)b * TC + tc) * 64 + lane];
        if (lab != 0)
            local += -logf(tot * (1.0f / T_DIM) + 1e-10f);

        unsigned long long nz = __ballot(lab != 0);
        if (lane == 0) {
            int len = __popcll(nz);
            float bs = 0.0f;
#pragma unroll
            for (int tc = 0; tc < TC; ++tc) bs += part_blank[b * TC + tc];
            local += -(float)(T_DIM - len) * logf(bs * (1.0f / T_DIM) + 1e-10f);
        }
    }

    // Wave-64 reduction, then cross-wave via LDS.
#pragma unroll
    for (int off = 32; off; off >>= 1) local += __shfl_down(local, off);

    __shared__ float r[16];
    if (lane == 0) r[w] = local;
    __syncthreads();
    if (tid == 0) {
        float s = 0.0f;
#pragma unroll
        for (int k = 0; k < 16; ++k) s += r[k];
        out[0] = s * (1.0f / ((float)T_DIM * (float)B_DIM));
    }
}

extern "C" void kernel_launch(void* const* d_in, const int* in_sizes, int n_in,
                              void* d_out, int out_size, void* d_ws, size_t ws_size,
                              hipStream_t stream) {
    const float* x     = (const float*)d_in[0];  // [T, B, V] float32
    const int*   label = (const int*)d_in[1];    // [B, L] int32
    float* out = (float*)d_out;

    float* part_label = (float*)d_ws;                          // 32*32*64 floats = 256 KB
    float* part_blank = part_label + (size_t)B_DIM * TC * 64;  // 1024 floats

    dim3 grid(B_DIM, TC);
    ACE_gather_k<<<grid, 256, 0, stream>>>(x, label, part_label, part_blank);
    ACE_finalize_k<<<1, 1024, 0, stream>>>(part_label, part_blank, label, out);
}